// Round 2
// baseline (1293.075 us; speedup 1.0000x reference)
//
#include <hip/hip_runtime.h>
#include <hip/hip_bf16.h>

// IntraPatchGraphAggregator: N=8192 patches, L=64, D=256, H=4, DH=64, TAU=300
// Fully fused: one workgroup (4 waves) per patch. bf16 MFMA (16x16x32), f32 accum.

typedef __attribute__((ext_vector_type(8))) short short8;   // 8 bf16 (4 VGPRs)
typedef __attribute__((ext_vector_type(4))) float f32x4;    // 4 fp32 accum

__device__ __forceinline__ unsigned short f2b(float x) {   // f32 -> bf16 RNE
  unsigned int u = __float_as_uint(x);
  u += 0x7FFFu + ((u >> 16) & 1u);
  return (unsigned short)(u >> 16);
}
__device__ __forceinline__ float b2f(unsigned short b) {
  return __uint_as_float(((unsigned int)b) << 16);
}

// ---- weight conversion: Wq|Wk|Wv -> Wqkv_b [768][256], Wo -> Wo_b [256][256]
__global__ void wconv_kernel(const float* __restrict__ Wq, const float* __restrict__ Wk,
                             const float* __restrict__ Wv, const float* __restrict__ Wo,
                             unsigned short* __restrict__ dst) {
  int e = blockIdx.x * 256 + threadIdx.x;   // 0 .. 262143
  int row = e >> 8, col = e & 255;
  float v;
  if (row < 256)      v = Wq[(row << 8) | col];
  else if (row < 512) v = Wk[((row - 256) << 8) | col];
  else if (row < 768) v = Wv[((row - 512) << 8) | col];
  else                v = Wo[((row - 768) << 8) | col];
  dst[e] = f2b(v);
}

__global__ __launch_bounds__(256, 2) void patch_attn_kernel(
    const float* __restrict__ tokens, const float* __restrict__ ts,
    const float* __restrict__ maskp,
    const unsigned short* __restrict__ Wqkv,  // [768][256] rows: Wq(0-255) Wk(256-511) Wv(512-767)
    const unsigned short* __restrict__ Wob,   // [256][256]
    const float* __restrict__ bq, const float* __restrict__ bk,
    const float* __restrict__ bv, const float* __restrict__ bo,
    const float* __restrict__ readout, float* __restrict__ outp) {
  // padded (+8 bf16 = 16B) to break power-of-2 LDS strides -> 2-way (free) conflicts
  __shared__ unsigned short Xb[64][264];    // tokens bf16; reused as masked `out` for pooling
  __shared__ unsigned short Qh[64][72];     // Q_h; reused for O_h
  __shared__ unsigned short Kh[64][72];
  __shared__ unsigned short VhT[64][72];    // V_h transposed: VhT[n][k] = V[k][n]
  __shared__ unsigned short Ah[64][72];     // softmax probs bf16
  __shared__ float tl[64];
  __shared__ float ml[64];
  __shared__ float ps[4][64];               // pooling probs per head

  const int n   = blockIdx.x;
  const int tid = threadIdx.x;
  const int w   = tid >> 6;    // wave 0..3
  const int l   = tid & 63;    // lane
  const int l16 = l & 15;
  const int lq  = l >> 4;      // quarter-wave 0..3

  if (tid < 64) { tl[tid] = ts[n * 64 + tid]; ml[tid] = maskp[n * 64 + tid]; }

  // ---- stage tokens -> bf16 LDS (coalesced float4, RNE convert)
  const float4* Xg = (const float4*)(tokens + (size_t)n * (64 * 256));
  #pragma unroll
  for (int it = 0; it < 16; ++it) {
    int p = tid + it * 256;            // float4 index 0..4095
    float4 v = Xg[p];
    int row = p >> 6, col = (p & 63) << 2;
    ushort4 b;
    b.x = f2b(v.x); b.y = f2b(v.y); b.z = f2b(v.z); b.w = f2b(v.w);
    *(ushort4*)&Xb[row][col] = b;
  }
  __syncthreads();

  const f32x4 fz = {0.f, 0.f, 0.f, 0.f};
  f32x4 oacc[4][4];                    // persistent: out rows 16rf.., cols 64w+16j..
  #pragma unroll
  for (int a = 0; a < 4; ++a)
    #pragma unroll
    for (int bb = 0; bb < 4; ++bb) oacc[a][bb] = fz;

  #pragma unroll 1
  for (int h = 0; h < 4; ++h) {
    // ================= QKV projection =================
    // wave w computes, for c in {Q,K,V}, head-local cols 16w..16w+15, ALL 64 rows.
    // Each weight fragment loaded exactly once per block.
    f32x4 qacc[4][3];
    #pragma unroll
    for (int rf = 0; rf < 4; ++rf)
      #pragma unroll
      for (int c = 0; c < 3; ++c) qacc[rf][c] = fz;

    const unsigned short* wp0 = Wqkv + (size_t)((0 * 256 + h * 64 + 16 * w + l16) * 256 + lq * 8);
    const unsigned short* wp1 = Wqkv + (size_t)((1 * 256 + h * 64 + 16 * w + l16) * 256 + lq * 8);
    const unsigned short* wp2 = Wqkv + (size_t)((2 * 256 + h * 64 + 16 * w + l16) * 256 + lq * 8);

    #pragma unroll
    for (int ks = 0; ks < 8; ++ks) {
      int k0 = ks * 32;
      short8 afr[4];
      #pragma unroll
      for (int rf = 0; rf < 4; ++rf)
        afr[rf] = *(const short8*)&Xb[16 * rf + l16][k0 + lq * 8];
      short8 bfr[3];
      bfr[0] = *(const short8*)(wp0 + k0);
      bfr[1] = *(const short8*)(wp1 + k0);
      bfr[2] = *(const short8*)(wp2 + k0);
      #pragma unroll
      for (int rf = 0; rf < 4; ++rf) {
        qacc[rf][0] = __builtin_amdgcn_mfma_f32_16x16x32_bf16(afr[rf], bfr[0], qacc[rf][0], 0, 0, 0);
        qacc[rf][1] = __builtin_amdgcn_mfma_f32_16x16x32_bf16(afr[rf], bfr[1], qacc[rf][1], 0, 0, 0);
        qacc[rf][2] = __builtin_amdgcn_mfma_f32_16x16x32_bf16(afr[rf], bfr[2], qacc[rf][2], 0, 0, 0);
      }
    }
    // writeback (+bias); V stored transposed
    {
      int ncol = 16 * w + l16;         // head-local output col 0..63
      float bqv = bq[h * 64 + ncol], bkv = bk[h * 64 + ncol], bvv = bv[h * 64 + ncol];
      #pragma unroll
      for (int rf = 0; rf < 4; ++rf) {
        #pragma unroll
        for (int i = 0; i < 4; ++i) {
          int m = 16 * rf + lq * 4 + i;          // C/D layout row
          Qh[m][ncol]  = f2b(qacc[rf][0][i] + bqv);
          Kh[m][ncol]  = f2b(qacc[rf][1][i] + bkv);
          VhT[ncol][m] = f2b(qacc[rf][2][i] + bvv);
        }
      }
    }
    __syncthreads();

    // ================= S = Q K^T (wave w: rows 16w..16w+15, all 64 cols) =====
    f32x4 sacc[4];
    #pragma unroll
    for (int j = 0; j < 4; ++j) sacc[j] = fz;
    #pragma unroll
    for (int ks = 0; ks < 2; ++ks) {
      int k0 = ks * 32;
      short8 aq = *(const short8*)&Qh[16 * w + l16][k0 + lq * 8];
      #pragma unroll
      for (int j = 0; j < 4; ++j) {
        short8 bk8 = *(const short8*)&Kh[16 * j + l16][k0 + lq * 8];
        sacc[j] = __builtin_amdgcn_mfma_f32_16x16x32_bf16(aq, bk8, sacc[j], 0, 0, 0);
      }
    }
    // bias (-dt/tau), key-pad mask, row softmax (quarter-wave shuffle reduce)
    {
      float tn[4], mn[4];
      #pragma unroll
      for (int j = 0; j < 4; ++j) { tn[j] = tl[16 * j + l16]; mn[j] = ml[16 * j + l16]; }
      #pragma unroll
      for (int i = 0; i < 4; ++i) {
        int m = 16 * w + lq * 4 + i;
        float tm = tl[m];
        float sv[4];
        #pragma unroll
        for (int j = 0; j < 4; ++j) {
          float s = sacc[j][i] * 0.125f - fabsf(tm - tn[j]) * (1.0f / 300.0f);
          sv[j] = (mn[j] <= 0.0f) ? -1e9f : s;
        }
        float mx = fmaxf(fmaxf(sv[0], sv[1]), fmaxf(sv[2], sv[3]));
        #pragma unroll
        for (int x = 1; x < 16; x <<= 1) mx = fmaxf(mx, __shfl_xor(mx, x));
        float pj[4], sum = 0.f;
        #pragma unroll
        for (int j = 0; j < 4; ++j) { pj[j] = __expf(sv[j] - mx); sum += pj[j]; }
        #pragma unroll
        for (int x = 1; x < 16; x <<= 1) sum += __shfl_xor(sum, x);
        float inv = 1.0f / sum;
        #pragma unroll
        for (int j = 0; j < 4; ++j) Ah[m][16 * j + l16] = f2b(pj[j] * inv);
      }
    }
    __syncthreads();

    // ================= O = A V (wave w: rows 16w..16w+15) =================
    f32x4 pacc[4];
    #pragma unroll
    for (int j = 0; j < 4; ++j) pacc[j] = fz;
    #pragma unroll
    for (int ks = 0; ks < 2; ++ks) {
      int k0 = ks * 32;
      short8 ap = *(const short8*)&Ah[16 * w + l16][k0 + lq * 8];
      #pragma unroll
      for (int j = 0; j < 4; ++j) {
        short8 bv8 = *(const short8*)&VhT[16 * j + l16][k0 + lq * 8];
        pacc[j] = __builtin_amdgcn_mfma_f32_16x16x32_bf16(ap, bv8, pacc[j], 0, 0, 0);
      }
    }
    // write O_h into Qh space (Q dead after S; all waves past Qh reads at Ah sync)
    #pragma unroll
    for (int j = 0; j < 4; ++j)
      #pragma unroll
      for (int i = 0; i < 4; ++i)
        Qh[16 * w + lq * 4 + i][16 * j + l16] = f2b(pacc[j][i]);
    __syncthreads();

    // ============ out += O_h @ Wo_h^T (wave w: cols 64w..64w+63, all rows) ====
    {
      const unsigned short* wop[4];
      #pragma unroll
      for (int j = 0; j < 4; ++j)
        wop[j] = Wob + (size_t)((64 * w + 16 * j + l16) * 256 + h * 64 + lq * 8);
      #pragma unroll
      for (int ks = 0; ks < 2; ++ks) {
        int k0 = ks * 32;
        short8 ao[4];
        #pragma unroll
        for (int rf = 0; rf < 4; ++rf)
          ao[rf] = *(const short8*)&Qh[16 * rf + l16][k0 + lq * 8];
        short8 bw[4];
        #pragma unroll
        for (int j = 0; j < 4; ++j) bw[j] = *(const short8*)(wop[j] + k0);
        #pragma unroll
        for (int rf = 0; rf < 4; ++rf)
          #pragma unroll
          for (int j = 0; j < 4; ++j)
            oacc[rf][j] = __builtin_amdgcn_mfma_f32_16x16x32_bf16(ao[rf], bw[j], oacc[rf][j], 0, 0, 0);
      }
    }
    __syncthreads();   // protect Qh/Kh/VhT overwrite by next head
  }

  // ---- epilogue: out = (O@Wo^T + bo) * mask  -> Xb (bf16) for pooling
  #pragma unroll
  for (int rf = 0; rf < 4; ++rf) {
    #pragma unroll
    for (int j = 0; j < 4; ++j) {
      int ncol = 64 * w + 16 * j + l16;
      float bov = bo[ncol];
      #pragma unroll
      for (int i = 0; i < 4; ++i) {
        int m = 16 * rf + lq * 4 + i;
        Xb[m][ncol] = f2b((oacc[rf][j][i] + bov) * ml[m]);
      }
    }
  }
  __syncthreads();

  // ---- learned-query pooling: wave w == head w; lane l == token l
  {
    float acc = 0.f;
    #pragma unroll
    for (int d0 = 0; d0 < 64; d0 += 4) {
      ushort4 o4 = *(const ushort4*)&Xb[l][w * 64 + d0];
      acc += b2f(o4.x) * readout[w * 64 + d0]
           + b2f(o4.y) * readout[w * 64 + d0 + 1]
           + b2f(o4.z) * readout[w * 64 + d0 + 2]
           + b2f(o4.w) * readout[w * 64 + d0 + 3];
    }
    float logit = acc * 0.125f;
    if (ml[l] <= 0.0f) logit = -1e9f;
    float mx = logit;
    #pragma unroll
    for (int x = 1; x < 64; x <<= 1) mx = fmaxf(mx, __shfl_xor(mx, x));
    float p = __expf(logit - mx);
    float sm = p;
    #pragma unroll
    for (int x = 1; x < 64; x <<= 1) sm += __shfl_xor(sm, x);
    ps[w][l] = p / sm;
  }
  __syncthreads();
  {
    // lane l == output dim within head w
    float o = 0.f;
    #pragma unroll
    for (int k = 0; k < 64; ++k) o += ps[w][k] * b2f(Xb[k][w * 64 + l]);
    outp[(size_t)n * 256 + w * 64 + l] = o;
  }
}

extern "C" void kernel_launch(void* const* d_in, const int* in_sizes, int n_in,
                              void* d_out, int out_size, void* d_ws, size_t ws_size,
                              hipStream_t stream) {
  const float* tokens  = (const float*)d_in[0];
  const float* ts      = (const float*)d_in[1];
  const float* mask    = (const float*)d_in[2];
  const float* Wq      = (const float*)d_in[3];
  const float* bq      = (const float*)d_in[4];
  const float* Wk      = (const float*)d_in[5];
  const float* bk      = (const float*)d_in[6];
  const float* Wv      = (const float*)d_in[7];
  const float* bv      = (const float*)d_in[8];
  const float* Wo      = (const float*)d_in[9];
  const float* bo      = (const float*)d_in[10];
  const float* readout = (const float*)d_in[11];
  (void)n_in; (void)out_size; (void)ws_size;

  unsigned short* Wqkv_b = (unsigned short*)d_ws;        // 768*256 bf16
  unsigned short* Wo_b   = Wqkv_b + 768 * 256;           // 256*256 bf16 (total 512 KB)

  const int n_patches = in_sizes[0] / (64 * 256);

  wconv_kernel<<<1024, 256, 0, stream>>>(Wq, Wk, Wv, Wo, Wqkv_b);
  patch_attn_kernel<<<n_patches, 256, 0, stream>>>(
      tokens, ts, mask, Wqkv_b, Wo_b, bq, bk, bv, bo, readout, (float*)d_out);
}